// Round 6
// baseline (311.482 us; speedup 1.0000x reference)
//
#include <hip/hip_runtime.h>
#include <cstdint>
#include <cfloat>

#define BATCH 16
#define NBOX 25200
#define CH 85
#define NCLS 80
#define CAP 512
#define ACC 48
#define MAXDET 300
#define RPB 64       // rows per block in pre_kernel (21.76 KB LDS -> ~7 blocks/CU)
#define CNTPAD 16    // ints per counter slot (64B line) to kill atomic line contention

typedef unsigned long long u64;

__device__ __forceinline__ u64 shflx64(u64 v, int m) {
    int lo = __shfl_xor((int)(unsigned)(v & 0xffffffffu), m);
    int hi = __shfl_xor((int)(unsigned)(v >> 32), m);
    return ((u64)(unsigned)hi << 32) | (u64)(unsigned)lo;
}

// ---------------- kernel A: staged per-row conf/argmax + bucket by (image,class)
// 256 threads stage 64 rows via async global->LDS, then 4 threads/row scan 20 classes.
__global__ __launch_bounds__(256) void pre_kernel(const float* __restrict__ p,
                                                  int* __restrict__ cnt,
                                                  u64* __restrict__ bucketKey) {
#pragma clang fp contract(off)
    __shared__ float s[RPB * CH];          // 21,760 B
    int tid = threadIdx.x;
    long blockRow = (long)blockIdx.x * RPB;

    const float4* p4 = (const float4*)(p + blockRow * CH);
    float4* s4 = (float4*)s;
    for (int t = tid; t < RPB * CH / 4; t += 256) {
        __builtin_amdgcn_global_load_lds(
            (const __attribute__((address_space(1))) void*)(p4 + t),
            (__attribute__((address_space(3))) void*)(s4 + (t & ~63)),
            16, 0, 0);
    }
    __syncthreads();

    int r = tid >> 2;                      // row 0..63
    int q = tid & 3;                       // class quarter [20q, 20q+20)
    const float* row = s + r * CH;
    float obj = row[4];

    float v = -FLT_MAX; int c = 1000;
    int c0 = q * 20;
    for (int k = 0; k < 20; k++) {
        float sc = row[5 + c0 + k] * obj;  // multiply-first, matches reference
        int cc = c0 + k;
        if (sc > v) { v = sc; c = cc; }    // strict > keeps first max
    }
    // combine the 4 quarter-lanes: (value desc, class asc) == np.argmax first-max
#pragma unroll
    for (int m = 1; m <= 2; m <<= 1) {
        float v2 = __shfl_xor(v, m);
        int   cz = __shfl_xor(c, m);
        if (v2 > v || (v2 == v && cz < c)) { v = v2; c = cz; }
    }

    if (q == 0 && obj > 0.25f && v > 0.25f) {
        int wid = (int)blockRow + r;
        int b   = wid / NBOX;
        int idx = wid - b * NBOX;          // < 25200 < 2^15
        u64 key = ((u64)__float_as_uint(v) << 22) | ((u64)(32767 - idx) << 7) | (u64)c;
        int bkt = b * NCLS + c;
        int pos = atomicAdd(&cnt[bkt * CNTPAD], 1);
        if (pos < CAP) bucketKey[(long)bkt * CAP + pos] = key;
    }
}

// ---------------- wave-wide bitonic sort over R*64 keys, descending -----------
template<int R>
__device__ __forceinline__ void wave_sort(u64 (&key)[R], int lane) {
#pragma unroll
    for (int k = 2; k <= 64; k <<= 1)
#pragma unroll
        for (int j = k >> 1; j > 0; j >>= 1) {
#pragma unroll
            for (int r = 0; r < R; r++) {
                u64 part = shflx64(key[r], j);
                int pos = (r << 6) | lane;
                bool keepmax = (((pos & k) == 0) == ((lane & j) == 0));
                u64 mx = key[r] > part ? key[r] : part;
                u64 mn = key[r] > part ? part : key[r];
                key[r] = keepmax ? mx : mn;
            }
        }
#pragma unroll
    for (int K = 128; K <= R * 64; K <<= 1) {
#pragma unroll
        for (int m = K >> 7; m >= 1; m >>= 1) {
#pragma unroll
            for (int r = 0; r < R; r++) if (!(r & m)) {
                int r2 = r | m;
                u64 a = key[r], d = key[r2];
                bool desc = (((r << 6) & K) == 0);
                u64 hi = a > d ? a : d, lo = a > d ? d : a;
                key[r]  = desc ? hi : lo;
                key[r2] = desc ? lo : hi;
            }
        }
#pragma unroll
        for (int j = 32; j > 0; j >>= 1) {
#pragma unroll
            for (int r = 0; r < R; r++) {
                u64 part = shflx64(key[r], j);
                int pos = (r << 6) | lane;
                bool keepmax = (((pos & K) == 0) == ((lane & j) == 0));
                u64 mx = key[r] > part ? key[r] : part;
                u64 mn = key[r] > part ? part : key[r];
                key[r] = keepmax ? mx : mn;
            }
        }
    }
}

// ---------------- kernel B core: register-resident greedy NMS for one bucket ---
template<int R>
__device__ __forceinline__ void nms_core(int lane, int b, int c, int n, long kbase,
                                         const float* __restrict__ p,
                                         const u64* __restrict__ bucketKey,
                                         u64* __restrict__ accKey, long obase) {
#pragma clang fp contract(off)
    u64 key[R];
#pragma unroll
    for (int r = 0; r < R; r++) {
        int pos = (r << 6) | lane;
        key[r] = (pos < n) ? bucketKey[kbase + pos] : 0ULL;
    }
    wave_sort<R>(key, lane);

    float off = (float)c * 4096.0f;
    float rx1[R], ry1[R], rx2[R], ry2[R], rar[R];
    int live = 0;
#pragma unroll
    for (int r = 0; r < R; r++) {
        int pos = (r << 6) | lane;
        rx1[r] = 0.f; ry1[r] = 0.f; rx2[r] = 0.f; ry2[r] = 0.f; rar[r] = 0.f;
        if (pos < n) {
            int idx = 32767 - (int)((key[r] >> 7) & 32767);
            const float* q = p + ((long)b * NBOX + idx) * CH;
            float x = q[0], y = q[1], w = q[2], h = q[3];
            float hw = w * 0.5f, hh = h * 0.5f;
            rx1[r] = (x - hw) + off; ry1[r] = (y - hh) + off;
            rx2[r] = (x + hw) + off; ry2[r] = (y + hh) + off;
            rar[r] = (rx2[r] - rx1[r]) * (ry2[r] - ry1[r]);
            live |= 1 << r;
        }
    }

    int nacc = 0;
    for (;;) {
        int i = -1;
#pragma unroll
        for (int r = 0; r < R; r++) {
            u64 mr = __ballot((live >> r) & 1);
            if (i < 0 && mr) i = (r << 6) + (int)__ffsll((long long)mr) - 1;
        }
        if (i < 0) break;
        int ro = i >> 6, owner = i & 63;

        u64 kk = 0; float sX1 = 0, sY1 = 0, sX2 = 0, sY2 = 0, sA = 0;
#pragma unroll
        for (int r = 0; r < R; r++) if (r == ro) {
            kk = key[r]; sX1 = rx1[r]; sY1 = ry1[r]; sX2 = rx2[r]; sY2 = ry2[r]; sA = rar[r];
        }
        if (lane == owner) {
            accKey[obase + nacc] = kk;
            live &= ~(1 << ro);
        }
        nacc++;
        if (nacc == ACC) break;

        float X1 = __shfl(sX1, owner), Y1 = __shfl(sY1, owner);
        float X2 = __shfl(sX2, owner), Y2 = __shfl(sY2, owner);
        float A  = __shfl(sA,  owner);

#pragma unroll
        for (int r = 0; r < R; r++) if ((live >> r) & 1) {
            float xx1 = fmaxf(X1, rx1[r]);
            float yy1 = fmaxf(Y1, ry1[r]);
            float xx2 = fminf(X2, rx2[r]);
            float yy2 = fminf(Y2, ry2[r]);
            float inter = fmaxf(xx2 - xx1, 0.0f) * fmaxf(yy2 - yy1, 0.0f);
            float uni = (A + rar[r]) - inter;
            if (inter / uni > 0.45f) live &= ~(1 << r);
        }
    }
    for (int t = nacc + lane; t < ACC; t += 64) accKey[obase + t] = 0ULL;
}

// 4 waves per block, each wave owns one (image,class) bucket. No LDS, no barriers.
__global__ __launch_bounds__(256) void nms_kernel(const float* __restrict__ p,
                                                  const int* __restrict__ cnt,
                                                  const u64* __restrict__ bucketKey,
                                                  u64* __restrict__ accKey) {
    int lane = threadIdx.x & 63;
    int bkt = (blockIdx.x << 2) | (threadIdx.x >> 6);
    int b = bkt / NCLS, c = bkt - b * NCLS;
    int n = cnt[bkt * CNTPAD]; if (n > CAP) n = CAP;
    long kbase = (long)bkt * CAP;
    long obase = (long)bkt * ACC;
    // n is wave-uniform; ~99% of buckets have n<=256 -> half-width sort network
    if (n <= 256) nms_core<4>(lane, b, c, n, kbase, p, bucketKey, accKey, obase);
    else          nms_core<8>(lane, b, c, n, kbase, p, bucketKey, accKey, obase);
}

// ---------------- kernel C: rank merge via linear broadcast count --------------
// rank(key) = count over ALL classes of entries > key (own list contributes own
// pos). All lanes scan the same list in lockstep -> wave-uniform LDS reads
// (broadcast, conflict-free), 24 independent b128 loads per class, no dependent
// chain. Per-8-class wave prune once every lane's rank >= 300.
__global__ __launch_bounds__(256) void merge_kernel(const float* __restrict__ p,
                                                    const u64* __restrict__ accKey,
                                                    float* __restrict__ outRows,
                                                    float* __restrict__ outKeep) {
#pragma clang fp contract(off)
    __shared__ u64 L[NCLS * ACC];          // 30,720 B
    int tid = threadIdx.x, b = blockIdx.y;
    const u64* src = accKey + (long)b * NCLS * ACC;
    for (int t = tid; t < NCLS * ACC; t += 256) L[t] = src[t];
    __syncthreads();

    int g = blockIdx.x * 256 + tid;        // 0..3839
    u64 key = L[g];
    int rank = 0;
    const ulonglong2* L2 = (const ulonglong2*)L;
    for (int c2 = 0; c2 < NCLS; c2++) {
        const ulonglong2* Lc = L2 + c2 * (ACC / 2);
        int cn = 0;
#pragma unroll
        for (int t2 = 0; t2 < ACC / 2; t2++) {
            ulonglong2 e = Lc[t2];
            cn += (e.x > key) ? 1 : 0;
            cn += (e.y > key) ? 1 : 0;
        }
        rank += cn;
        if ((c2 & 7) == 7) {
            if (__ballot(key != 0ULL && rank < MAXDET) == 0ULL) return;
        }
    }
    if (key == 0ULL || rank >= MAXDET) return;

    int cc  = (int)(key & 127);
    int idx = 32767 - (int)((key >> 7) & 32767);
    float conf = __uint_as_float((unsigned)(key >> 22));
    const float* q = p + ((long)b * NBOX + idx) * CH;
    float x = q[0], y = q[1], w = q[2], h = q[3];
    float hw = w * 0.5f, hh = h * 0.5f;
    float* row = outRows + ((long)b * MAXDET + rank) * 6;
    row[0] = x - hw; row[1] = y - hh; row[2] = x + hw; row[3] = y + hh;
    row[4] = conf;   row[5] = (float)cc;
    outKeep[b * MAXDET + rank] = 1.0f;
}

extern "C" void kernel_launch(void* const* d_in, const int* in_sizes, int n_in,
                              void* d_out, int out_size, void* d_ws, size_t ws_size,
                              hipStream_t stream) {
    const float* p = (const float*)d_in[0];
    float* out = (float*)d_out;

    char* ws = (char*)d_ws;
    int* cnt = (int*)ws;                                   // 1280 * 64B padded counters
    u64* bucketKey = (u64*)(ws + BATCH * NCLS * CNTPAD * 4);               // 5.24 MB
    u64* accKey    = (u64*)(ws + BATCH * NCLS * CNTPAD * 4
                               + (size_t)BATCH * NCLS * CAP * 8);          // 491 KB

    hipMemsetAsync(cnt, 0, BATCH * NCLS * CNTPAD * sizeof(int), stream);
    hipMemsetAsync(out, 0, (size_t)out_size * sizeof(float), stream);
    pre_kernel<<<(BATCH * NBOX) / RPB, 256, 0, stream>>>(p, cnt, bucketKey);
    nms_kernel<<<BATCH * NCLS / 4, 256, 0, stream>>>(p, cnt, bucketKey, accKey);
    dim3 gM(NCLS * ACC / 256, BATCH);
    merge_kernel<<<gM, 256, 0, stream>>>(p, accKey, out, out + (size_t)BATCH * MAXDET * 6);
}

// Round 7
// 308.244 us; speedup vs baseline: 1.0105x; 1.0105x over previous
//
#include <hip/hip_runtime.h>
#include <cstdint>
#include <cfloat>

#define BATCH 16
#define NBOX 25200
#define CH 85
#define NCLS 80
#define CAP 512
#define ACC 48
#define MAXDET 300
#define RPW 16       // rows per wave in pre_kernel (wave-local staging, no barriers)
#define CNTPAD 16    // ints per counter slot (64B line) to kill atomic line contention

typedef unsigned long long u64;

__device__ __forceinline__ u64 shflx64(u64 v, int m) {
    int lo = __shfl_xor((int)(unsigned)(v & 0xffffffffu), m);
    int hi = __shfl_xor((int)(unsigned)(v >> 32), m);
    return ((u64)(unsigned)hi << 32) | (u64)(unsigned)lo;
}

// ---------------- kernel Z: fused zeroing of counters + output -----------------
__global__ __launch_bounds__(256) void zero_kernel(int* __restrict__ cnt,
                                                   float* __restrict__ out, int outN) {
    int t = blockIdx.x * 256 + threadIdx.x;
    if (t < BATCH * NCLS * CNTPAD) cnt[t] = 0;
    if (t < outN) out[t] = 0.0f;
}

// ---------------- kernel A: wave-local staged conf/argmax + bucketing ----------
// Each wave stages its own 16 rows into LDS via global_load_lds, waits only on
// its own vmcnt (no __syncthreads anywhere), then 4 lanes/row scan 20 classes.
__global__ __launch_bounds__(256) void pre_kernel(const float* __restrict__ p,
                                                  int* __restrict__ cnt,
                                                  u64* __restrict__ bucketKey) {
#pragma clang fp contract(off)
    __shared__ float s[4 * RPW * CH];      // 4 waves * 16 rows * 85 = 21,760 B
    int tid = threadIdx.x;
    int w = tid >> 6, lane = tid & 63;
    long waveRow = (long)blockIdx.x * (4 * RPW) + w * RPW;

    const float4* p4 = (const float4*)(p + waveRow * CH);   // 340 float4 per wave
    float* sw = s + w * (RPW * CH);
    float4* s4 = (float4*)sw;
#pragma unroll
    for (int t = 0; t < 6; t++) {
        int e = t * 64 + lane;
        if (e < RPW * CH / 4)
            __builtin_amdgcn_global_load_lds(
                (const __attribute__((address_space(1))) void*)(p4 + e),
                (__attribute__((address_space(3))) void*)(s4 + t * 64),
                16, 0, 0);
    }
    // wait for THIS wave's loads only: vmcnt(0), lgkmcnt/expcnt = no-wait
    __builtin_amdgcn_s_waitcnt(0x0F70);

    int r = lane >> 2;                     // row 0..15 within wave
    int q = lane & 3;                      // class quarter [20q, 20q+20)
    const float* row = sw + r * CH;
    float obj = row[4];

    float v = -FLT_MAX; int c = 1000;
    int c0 = q * 20;
    for (int k = 0; k < 20; k++) {
        float sc = row[5 + c0 + k] * obj;  // multiply-first, matches reference
        int cc = c0 + k;
        if (sc > v) { v = sc; c = cc; }    // strict > keeps first max
    }
    // combine the 4 quarter-lanes: (value desc, class asc) == np.argmax first-max
#pragma unroll
    for (int m = 1; m <= 2; m <<= 1) {
        float v2 = __shfl_xor(v, m);
        int   cz = __shfl_xor(c, m);
        if (v2 > v || (v2 == v && cz < c)) { v = v2; c = cz; }
    }

    if (q == 0 && obj > 0.25f && v > 0.25f) {
        int wid = (int)waveRow + r;
        int b   = wid / NBOX;
        int idx = wid - b * NBOX;          // < 25200 < 2^15
        u64 key = ((u64)__float_as_uint(v) << 22) | ((u64)(32767 - idx) << 7) | (u64)c;
        int bkt = b * NCLS + c;
        int pos = atomicAdd(&cnt[bkt * CNTPAD], 1);
        if (pos < CAP) bucketKey[(long)bkt * CAP + pos] = key;
    }
}

// ---------------- wave-wide bitonic sort over R*64 keys, descending -----------
template<int R>
__device__ __forceinline__ void wave_sort(u64 (&key)[R], int lane) {
#pragma unroll
    for (int k = 2; k <= 64; k <<= 1)
#pragma unroll
        for (int j = k >> 1; j > 0; j >>= 1) {
#pragma unroll
            for (int r = 0; r < R; r++) {
                u64 part = shflx64(key[r], j);
                int pos = (r << 6) | lane;
                bool keepmax = (((pos & k) == 0) == ((lane & j) == 0));
                u64 mx = key[r] > part ? key[r] : part;
                u64 mn = key[r] > part ? part : key[r];
                key[r] = keepmax ? mx : mn;
            }
        }
#pragma unroll
    for (int K = 128; K <= R * 64; K <<= 1) {
#pragma unroll
        for (int m = K >> 7; m >= 1; m >>= 1) {
#pragma unroll
            for (int r = 0; r < R; r++) if (!(r & m)) {
                int r2 = r | m;
                u64 a = key[r], d = key[r2];
                bool desc = (((r << 6) & K) == 0);
                u64 hi = a > d ? a : d, lo = a > d ? d : a;
                key[r]  = desc ? hi : lo;
                key[r2] = desc ? lo : hi;
            }
        }
#pragma unroll
        for (int j = 32; j > 0; j >>= 1) {
#pragma unroll
            for (int r = 0; r < R; r++) {
                u64 part = shflx64(key[r], j);
                int pos = (r << 6) | lane;
                bool keepmax = (((pos & K) == 0) == ((lane & j) == 0));
                u64 mx = key[r] > part ? key[r] : part;
                u64 mn = key[r] > part ? part : key[r];
                key[r] = keepmax ? mx : mn;
            }
        }
    }
}

// ---------------- kernel B core: register-resident greedy NMS for one bucket ---
template<int R>
__device__ __forceinline__ void nms_core(int lane, int b, int c, int n, long kbase,
                                         const float* __restrict__ p,
                                         const u64* __restrict__ bucketKey,
                                         u64* __restrict__ accKey, long obase) {
#pragma clang fp contract(off)
    u64 key[R];
#pragma unroll
    for (int r = 0; r < R; r++) {
        int pos = (r << 6) | lane;
        key[r] = (pos < n) ? bucketKey[kbase + pos] : 0ULL;
    }
    wave_sort<R>(key, lane);

    float off = (float)c * 4096.0f;
    float rx1[R], ry1[R], rx2[R], ry2[R], rar[R];
    int live = 0;
#pragma unroll
    for (int r = 0; r < R; r++) {
        int pos = (r << 6) | lane;
        rx1[r] = 0.f; ry1[r] = 0.f; rx2[r] = 0.f; ry2[r] = 0.f; rar[r] = 0.f;
        if (pos < n) {
            int idx = 32767 - (int)((key[r] >> 7) & 32767);
            const float* q = p + ((long)b * NBOX + idx) * CH;
            float x = q[0], y = q[1], w = q[2], h = q[3];
            float hw = w * 0.5f, hh = h * 0.5f;
            rx1[r] = (x - hw) + off; ry1[r] = (y - hh) + off;
            rx2[r] = (x + hw) + off; ry2[r] = (y + hh) + off;
            rar[r] = (rx2[r] - rx1[r]) * (ry2[r] - ry1[r]);
            live |= 1 << r;
        }
    }

    int nacc = 0;
    for (;;) {
        int i = -1;
#pragma unroll
        for (int r = 0; r < R; r++) {
            u64 mr = __ballot((live >> r) & 1);
            if (i < 0 && mr) i = (r << 6) + (int)__ffsll((long long)mr) - 1;
        }
        if (i < 0) break;
        int ro = i >> 6, owner = i & 63;

        u64 kk = 0; float sX1 = 0, sY1 = 0, sX2 = 0, sY2 = 0, sA = 0;
#pragma unroll
        for (int r = 0; r < R; r++) if (r == ro) {
            kk = key[r]; sX1 = rx1[r]; sY1 = ry1[r]; sX2 = rx2[r]; sY2 = ry2[r]; sA = rar[r];
        }
        if (lane == owner) {
            accKey[obase + nacc] = kk;
            live &= ~(1 << ro);
        }
        nacc++;
        if (nacc == ACC) break;

        float X1 = __shfl(sX1, owner), Y1 = __shfl(sY1, owner);
        float X2 = __shfl(sX2, owner), Y2 = __shfl(sY2, owner);
        float A  = __shfl(sA,  owner);

#pragma unroll
        for (int r = 0; r < R; r++) if ((live >> r) & 1) {
            float xx1 = fmaxf(X1, rx1[r]);
            float yy1 = fmaxf(Y1, ry1[r]);
            float xx2 = fminf(X2, rx2[r]);
            float yy2 = fminf(Y2, ry2[r]);
            float inter = fmaxf(xx2 - xx1, 0.0f) * fmaxf(yy2 - yy1, 0.0f);
            float uni = (A + rar[r]) - inter;
            if (inter / uni > 0.45f) live &= ~(1 << r);
        }
    }
    for (int t = nacc + lane; t < ACC; t += 64) accKey[obase + t] = 0ULL;
}

// 4 waves per block, each wave owns one (image,class) bucket. No LDS, no barriers.
__global__ __launch_bounds__(256) void nms_kernel(const float* __restrict__ p,
                                                  const int* __restrict__ cnt,
                                                  const u64* __restrict__ bucketKey,
                                                  u64* __restrict__ accKey) {
    int lane = threadIdx.x & 63;
    int bkt = (blockIdx.x << 2) | (threadIdx.x >> 6);
    int b = bkt / NCLS, c = bkt - b * NCLS;
    int n = cnt[bkt * CNTPAD]; if (n > CAP) n = CAP;
    long kbase = (long)bkt * CAP;
    long obase = (long)bkt * ACC;
    // n is wave-uniform; virtually all buckets have n<=256 -> half-width network
    if (n <= 256) nms_core<4>(lane, b, c, n, kbase, p, bucketKey, accKey, obase);
    else          nms_core<8>(lane, b, c, n, kbase, p, bucketKey, accKey, obase);
}

// ---------------- kernel C: rank merge via linear broadcast count --------------
__global__ __launch_bounds__(256) void merge_kernel(const float* __restrict__ p,
                                                    const u64* __restrict__ accKey,
                                                    float* __restrict__ outRows,
                                                    float* __restrict__ outKeep) {
#pragma clang fp contract(off)
    __shared__ u64 L[NCLS * ACC];          // 30,720 B
    int tid = threadIdx.x, b = blockIdx.y;
    const u64* src = accKey + (long)b * NCLS * ACC;
    for (int t = tid; t < NCLS * ACC; t += 256) L[t] = src[t];
    __syncthreads();

    int g = blockIdx.x * 256 + tid;        // 0..3839
    u64 key = L[g];
    int rank = 0;
    const ulonglong2* L2 = (const ulonglong2*)L;
    for (int c2 = 0; c2 < NCLS; c2++) {
        const ulonglong2* Lc = L2 + c2 * (ACC / 2);
        int cn = 0;
#pragma unroll
        for (int t2 = 0; t2 < ACC / 2; t2++) {
            ulonglong2 e = Lc[t2];
            cn += (e.x > key) ? 1 : 0;
            cn += (e.y > key) ? 1 : 0;
        }
        rank += cn;
        if ((c2 & 7) == 7) {
            if (__ballot(key != 0ULL && rank < MAXDET) == 0ULL) return;
        }
    }
    if (key == 0ULL || rank >= MAXDET) return;

    int cc  = (int)(key & 127);
    int idx = 32767 - (int)((key >> 7) & 32767);
    float conf = __uint_as_float((unsigned)(key >> 22));
    const float* q = p + ((long)b * NBOX + idx) * CH;
    float x = q[0], y = q[1], w = q[2], h = q[3];
    float hw = w * 0.5f, hh = h * 0.5f;
    float* row = outRows + ((long)b * MAXDET + rank) * 6;
    row[0] = x - hw; row[1] = y - hh; row[2] = x + hw; row[3] = y + hh;
    row[4] = conf;   row[5] = (float)cc;
    outKeep[b * MAXDET + rank] = 1.0f;
}

extern "C" void kernel_launch(void* const* d_in, const int* in_sizes, int n_in,
                              void* d_out, int out_size, void* d_ws, size_t ws_size,
                              hipStream_t stream) {
    const float* p = (const float*)d_in[0];
    float* out = (float*)d_out;

    char* ws = (char*)d_ws;
    int* cnt = (int*)ws;                                   // 1280 * 64B padded counters
    u64* bucketKey = (u64*)(ws + BATCH * NCLS * CNTPAD * 4);               // 5.24 MB
    u64* accKey    = (u64*)(ws + BATCH * NCLS * CNTPAD * 4
                               + (size_t)BATCH * NCLS * CAP * 8);          // 491 KB

    int zeroN = (BATCH * NCLS * CNTPAD > out_size) ? BATCH * NCLS * CNTPAD : out_size;
    zero_kernel<<<(zeroN + 255) / 256, 256, 0, stream>>>(cnt, out, out_size);
    pre_kernel<<<(BATCH * NBOX) / (4 * RPW), 256, 0, stream>>>(p, cnt, bucketKey);
    nms_kernel<<<BATCH * NCLS / 4, 256, 0, stream>>>(p, cnt, bucketKey, accKey);
    dim3 gM(NCLS * ACC / 256, BATCH);
    merge_kernel<<<gM, 256, 0, stream>>>(p, accKey, out, out + (size_t)BATCH * MAXDET * 6);
}